// Round 10
// baseline (151.718 us; speedup 1.0000x reference)
//
#include <hip/hip_runtime.h>
#include <hip/hip_fp16.h>

// Problem: inputs (8, 64, 16, 32, 32) fp32, embedding (1024, 64) fp32
#define THW    16384
#define NTOT   131072
#define KDIM   1024
#define CDIM   64
#define QELEMS 8388608          // 8*64*16*32*32
#define LOSS_OFF 8388608
#define IDX_OFF  8388610
#define BN     128              // queries per block (4 waves x 32 queries)

typedef _Float16 half8   __attribute__((ext_vector_type(8)));
typedef _Float16 half4_t __attribute__((ext_vector_type(4)));
typedef float    f32x4   __attribute__((ext_vector_type(4)));

// ---- prep: zero losses; split E into fp16 hi/lo (lo scaled 2^12), packed as
// ONE 4 KB block per 16-code tile, in MFMA-fragment lane order:
//   halves dst = tile*2048 + kh*512 + (lq*16+ln)*8 + j   (hi)
//                + 1024 (lo)
// where code row = tile*16+ln, c = kh*32 + lq*8 + j.
// Also me2h[row] = -0.5*||e||^2.
__global__ __launch_bounds__(256) void vq_prep(const float* __restrict__ emb,
        _Float16* __restrict__ EF, float* __restrict__ me2h, float* __restrict__ out) {
    const int t = threadIdx.x;
    if (blockIdx.x == 0 && t == 0) { out[LOSS_OFF] = 0.f; out[LOSS_OFF + 1] = 0.f; }
    const int ln   = t >> 4;
    const int g    = t & 15;
    const int tile = blockIdx.x;
    const int row  = tile * 16 + ln;
    const int c0   = g * 4;
    float4 v = *(const float4*)(emb + (size_t)row * CDIM + c0);
    const float xs[4] = {v.x, v.y, v.z, v.w};
    half4_t h, l;
    float s = 0.f;
    #pragma unroll
    for (int j = 0; j < 4; ++j) {
        const _Float16 hj = (_Float16)xs[j];
        const _Float16 lj = (_Float16)((xs[j] - (float)hj) * 4096.0f);
        h[j] = hj; l[j] = lj;
        s = fmaf(xs[j], xs[j], s);
    }
    const int kh = c0 >> 5;
    const int lq = (c0 & 31) >> 3;
    const int j0 = c0 & 7;
    const size_t dst = (size_t)tile * 2048 + kh * 512 + (lq * 16 + ln) * 8 + j0;
    *(half4_t*)(EF + dst)        = h;
    *(half4_t*)(EF + dst + 1024) = l;
    #pragma unroll
    for (int off = 1; off < 16; off <<= 1) s += __shfl_xor(s, off, 64);
    if (g == 0) me2h[row] = -0.5f * s;
}

// ---- main: double-buffered LDS-staged E tiles; 4 waves ds_read fragments ----
__global__ __launch_bounds__(256, 4) void vq_main(const float* __restrict__ in,
        const float* __restrict__ emb,
        const _Float16* __restrict__ EF,
        const float* __restrict__ me2h, float* __restrict__ out) {

    __shared__ char smem[36416];
    float (*Xs)[68] = (float (*)[68])smem;                 // [128][68] prologue
    float (*Q)[68]  = (float (*)[68])smem;                 // epilogue alias
    float4* Eb      = (float4*)smem;                       // k-loop alias: [2][256] float4 (8 KB)
    float* x2p  = (float*)(smem + 34816);                  // [2][128]
    int*   idxs = (int*)(smem + 35840);                    // [128]
    float* wsum = (float*)(smem + 36352);                  // [4]

    const int tid  = threadIdx.x;
    const int n0   = blockIdx.x * BN;
    const int bb   = n0 >> 14;
    const int thw0 = n0 & (THW - 1);
    const float* inb = in  + (size_t)bb * CDIM * THW + thw0;
    float*      outb = out + (size_t)bb * CDIM * THW + thw0;

    // ---- stage X tile ([n][c] transpose) + ||x||^2 partials ----
    {
        const int nl = tid & 127;
        const int hf = tid >> 7;
        float s = 0.f;
        #pragma unroll 8
        for (int r = 0; r < 32; ++r) {
            const int c = hf * 32 + r;
            const float x = inb[(size_t)c * THW + nl];
            Xs[nl][c] = x;
            s = fmaf(x, x, s);
        }
        x2p[hf * 128 + nl] = s;
    }
    __syncthreads();

    const int lane = tid & 63;
    const int w    = tid >> 6;      // wave owns queries w*32 .. w*32+31
    const int ln   = lane & 15;
    const int lq   = lane >> 4;

    // ---- B fragments (fp16 hi/lo), register-resident ----
    half8 Bh[2][2], Bl[2][2];
    #pragma unroll
    for (int qg = 0; qg < 2; ++qg) {
        const int q = w * 32 + qg * 16 + ln;
        #pragma unroll
        for (int ch = 0; ch < 2; ++ch) {
            const float* xp = &Xs[q][ch * 32 + lq * 8];
            const float4 xa = *(const float4*)(xp);
            const float4 xb = *(const float4*)(xp + 4);
            const float xv[8] = {xa.x, xa.y, xa.z, xa.w, xb.x, xb.y, xb.z, xb.w};
            #pragma unroll
            for (int j = 0; j < 8; ++j) {
                const _Float16 h = (_Float16)xv[j];
                const _Float16 l = (_Float16)((xv[j] - (float)h) * 4096.0f);
                Bh[qg][ch][j] = h;
                Bl[qg][ch][j] = l;
            }
        }
    }
    __syncthreads();   // Xs dead; Ebuf region reusable

    // maximize s = x.e - 0.5*||e||^2  (argmax s == argmin d, d = -2s)
    float bests[2] = {-3.4e38f, -3.4e38f};
    int   besti[2] = {0, 0};

    const float4* EFp = (const float4*)EF;              // tile m at +m*256
    const f32x4*  pe4 = (const f32x4*)me2h + lq;        // tile m at +m*4

    // e2 seed ping-pong + stage tile 0 into Ebuf[0]
    f32x4 e2r[2];
    e2r[0] = pe4[0];
    {
        const float4 s0 = EFp[tid];                     // tile 0, 16 B/thread
        Eb[tid] = s0;                                   // ds_write_b128
    }
    __syncthreads();                                    // tile 0 visible

    #pragma unroll 2
    for (int m = 0; m < 64; ++m) {
        const int p = m & 1;
        // early: kick next tile's staging load + next e2 (full tile to land)
        float4 stg;
        if (m < 63) {
            stg = EFp[(size_t)(m + 1) * 256 + tid];
            e2r[p ^ 1] = pe4[(m + 1) * 4];
        }
        // A fragments from LDS (fragment-major: lane*16B, +1KB per part)
        const half8* eb = (const half8*)(smem + p * 4096);
        const half8 Ah0 = eb[lane];
        const half8 Ah1 = eb[64 + lane];
        const half8 Al0 = eb[128 + lane];
        const half8 Al1 = eb[192 + lane];

        #pragma unroll
        for (int qg = 0; qg < 2; ++qg) {
            // cross terms first (scaled 2^12)
            f32x4 a1 = {0.f, 0.f, 0.f, 0.f};
            a1 = __builtin_amdgcn_mfma_f32_16x16x32_f16(Ah0, Bl[qg][0], a1, 0, 0, 0);
            a1 = __builtin_amdgcn_mfma_f32_16x16x32_f16(Al0, Bh[qg][0], a1, 0, 0, 0);
            a1 = __builtin_amdgcn_mfma_f32_16x16x32_f16(Ah1, Bl[qg][1], a1, 0, 0, 0);
            a1 = __builtin_amdgcn_mfma_f32_16x16x32_f16(Al1, Bh[qg][1], a1, 0, 0, 0);
            // seed hh-chain with 2^-12*a1 - 0.5*||e||^2
            f32x4 c0;
            #pragma unroll
            for (int r = 0; r < 4; ++r)
                c0[r] = fmaf(2.44140625e-4f, a1[r], e2r[p][r]);
            c0 = __builtin_amdgcn_mfma_f32_16x16x32_f16(Ah0, Bh[qg][0], c0, 0, 0, 0);
            c0 = __builtin_amdgcn_mfma_f32_16x16x32_f16(Ah1, Bh[qg][1], c0, 0, 0, 0);
            // fold: bare compare (ascending k, strict > keeps lowest k)
            #pragma unroll
            for (int r = 0; r < 4; ++r) {
                const int kg = m * 16 + lq * 4 + r;
                if (c0[r] > bests[qg]) { bests[qg] = c0[r]; besti[qg] = kg; }
            }
        }
        // late: commit next tile into the other buffer, then barrier
        if (m < 63) Eb[(p ^ 1) * 256 + tid] = stg;
        __syncthreads();
    }

    // ---- wave-internal argmax reduce across the 4 row-quads ----
    #pragma unroll
    for (int qg = 0; qg < 2; ++qg) {
        #pragma unroll
        for (int msk = 16; msk <= 32; msk <<= 1) {
            const float ov = __shfl_xor(bests[qg], msk, 64);
            const int   oi = __shfl_xor(besti[qg], msk, 64);
            if (ov > bests[qg] || (ov == bests[qg] && oi < besti[qg])) {
                bests[qg] = ov; besti[qg] = oi;
            }
        }
    }
    float lsum = 0.f;
    if (lq == 0) {
        #pragma unroll
        for (int qg = 0; qg < 2; ++qg) {
            const int q = w * 32 + qg * 16 + ln;
            idxs[q] = besti[qg];
            out[IDX_OFF + n0 + q] = (float)besti[qg];
            // d = -2*s ; loss term = d + ||x||^2
            lsum += fmaf(-2.0f, bests[qg], x2p[q] + x2p[128 + q]);
        }
    }
    #pragma unroll
    for (int off = 32; off > 0; off >>= 1) lsum += __shfl_down(lsum, off, 64);
    if (lane == 0) wsum[w] = lsum;
    __syncthreads();
    if (tid == 0) {
        const float s = wsum[0] + wsum[1] + wsum[2] + wsum[3];
        atomicAdd(&out[LOSS_OFF],     s * (1.0f  / (float)QELEMS));
        atomicAdd(&out[LOSS_OFF + 1], s * (0.25f / (float)QELEMS));
    }

    // ---- epilogue: gather code rows into LDS (Q aliases dead Xs/Ebuf) ----
    {
        const int q  = tid >> 1;
        const int hf = tid & 1;
        const float* er = emb + (size_t)idxs[q] * CDIM + hf * 32;
        #pragma unroll
        for (int j = 0; j < 8; ++j) {
            const float4 v = *(const float4*)(er + 4 * j);
            *(float4*)(&Q[q][hf * 32 + 4 * j]) = v;
        }
    }
    __syncthreads();
    {
        const int nl = tid & 127;
        const int cb = tid >> 7;
        #pragma unroll 8
        for (int r = 0; r < 32; ++r) {
            const int c = 2 * r + cb;
            outb[(size_t)c * THW + nl] = Q[nl][c];
        }
    }
}

extern "C" void kernel_launch(void* const* d_in, const int* in_sizes, int n_in,
                              void* d_out, int out_size, void* d_ws, size_t ws_size,
                              hipStream_t stream) {
    const float* in  = (const float*)d_in[0];   // (8, 64, 16, 32, 32) fp32
    const float* emb = (const float*)d_in[1];   // (1024, 64) fp32
    float* out = (float*)d_out;
    _Float16* EF   = (_Float16*)d_ws;                       // 64 tiles * 4 KB = 256 KB
    float*    me2h = (float*)((char*)d_ws + 262144);        // 1024 floats = -0.5*||e||^2

    vq_prep<<<KDIM / 16, 256, 0, stream>>>(emb, EF, me2h, out);
    vq_main<<<NTOT / BN, 256, 0, stream>>>(in, emb, EF, me2h, out);
}